// Round 7
// baseline (3440.493 us; speedup 1.0000x reference)
//
#include <hip/hip_runtime.h>

typedef unsigned short u16;
typedef unsigned int u32;

#define NPTS 131072
#define CD 128
#define KOFF 27
#define MMAP 65536
#define TOT (KOFF * MMAP)      // 1769472 entries per conv
#define NBLK 2048              // output row blocks (64 rows each)
#define NBIN (NBLK * KOFF)     // 55296 sort bins
#define LDA 132                // LDS f32 accumulator row stride

__device__ __forceinline__ u16 f2bf(float f) {  // f32 -> bf16 RNE
  u32 u = __float_as_uint(f);
  u32 r = (u + 0x7fffu + ((u >> 16) & 1u)) >> 16;
  return (u16)r;
}

typedef __attribute__((ext_vector_type(8))) short bf16x8;
typedef __attribute__((ext_vector_type(4))) float f32x4;

// ---------------- dtype conversion ----------------
__global__ __launch_bounds__(256) void k_convert_x(const float* __restrict__ x,
                                                   u16* __restrict__ xb) {
  long i = ((long)blockIdx.x * 256 + threadIdx.x) * 8;
  float4 a = *(const float4*)(x + i);
  float4 b = *(const float4*)(x + i + 4);
  uint4 v;
  v.x = f2bf(a.x) | ((u32)f2bf(a.y) << 16);
  v.y = f2bf(a.z) | ((u32)f2bf(a.w) << 16);
  v.z = f2bf(b.x) | ((u32)f2bf(b.y) << 16);
  v.w = f2bf(b.z) | ((u32)f2bf(b.w) << 16);
  *(uint4*)(xb + i) = v;
}

// W [K][ci][co] f32 -> Wb [K][co][ci] bf16
__global__ __launch_bounds__(256) void k_convert_w(const float* __restrict__ W,
                                                   u16* __restrict__ Wb) {
  int idx = blockIdx.x * 256 + threadIdx.x;
  if (idx >= KOFF * 2048) return;
  int k = idx >> 11;
  int rem = idx & 2047;
  int co = rem >> 4;
  int cc = rem & 15;
  const float* ws = W + (long)k * (CD * CD) + (long)(cc * 8) * CD + co;
  u16 t[8];
#pragma unroll
  for (int j = 0; j < 8; ++j) t[j] = f2bf(ws[j * CD]);
  uint4 v;
  v.x = t[0] | ((u32)t[1] << 16);
  v.y = t[2] | ((u32)t[3] << 16);
  v.z = t[4] | ((u32)t[5] << 16);
  v.w = t[6] | ((u32)t[7] << 16);
  ((uint4*)Wb)[idx] = v;
}

// ---------------- counting sort over (row_block, k) bins ----------------
__global__ __launch_bounds__(256) void k_hist3(const int* __restrict__ mo,
                                               u32* __restrict__ hist) {
  int i = blockIdx.x * 256 + threadIdx.x;  // grid = TOT/256 exact
  u32 key = ((u32)mo[i] >> 6) * KOFF + (u32)(i >> 16);
  atomicAdd(&hist[key], 1u);
}

__global__ __launch_bounds__(256) void k_scanA3(const u32* __restrict__ hist,
                                                u32* __restrict__ offs,
                                                u32* __restrict__ bsum) {
  __shared__ u32 sh[256];
  int t = threadIdx.x, b = blockIdx.x, i = b * 256 + t;  // 216 blocks, NBIN exact
  u32 v = hist[i];
  u32 run = v;
  sh[t] = run;
  __syncthreads();
  for (int d = 1; d < 256; d <<= 1) {
    u32 y = (t >= d) ? sh[t - d] : 0u;
    __syncthreads();
    run += y;
    sh[t] = run;
    __syncthreads();
  }
  offs[i] = run - v;
  if (t == 255) bsum[b] = run;
}

__global__ __launch_bounds__(256) void k_scanB3(u32* __restrict__ bsum) {
  __shared__ u32 sh[256];
  int t = threadIdx.x;
  u32 v = (t < 216) ? bsum[t] : 0u;
  u32 run = v;
  sh[t] = run;
  __syncthreads();
  for (int d = 1; d < 256; d <<= 1) {
    u32 y = (t >= d) ? sh[t - d] : 0u;
    __syncthreads();
    run += y;
    sh[t] = run;
    __syncthreads();
  }
  if (t < 216) bsum[t] = run - v;
}

__global__ __launch_bounds__(256) void k_scanC3(u32* __restrict__ offs,
                                                const u32* __restrict__ bsum) {
  int t = threadIdx.x, b = blockIdx.x, i = b * 256 + t;
  offs[i] += bsum[b];
  if (i == 0) offs[NBIN] = (u32)TOT;
}

// sidx[rank] = packed entry: (input_row << 6) | (out_row & 63). One coalesced load in k_fconv.
__global__ __launch_bounds__(256) void k_rank3(const int* __restrict__ mi,
                                               const int* __restrict__ mo,
                                               const u32* __restrict__ offs,
                                               u32* __restrict__ cur,
                                               u32* __restrict__ sidx) {
  int i = blockIdx.x * 256 + threadIdx.x;
  u32 o = (u32)mo[i];
  u32 key = (o >> 6) * KOFF + (u32)(i >> 16);
  u32 r = offs[key] + atomicAdd(&cur[key], 1u);
  sidx[r] = ((u32)mi[i] << 6) | (o & 63u);
}

// ---------------- fused implicit-GEMM sparse conv with LDS cross-k reduction ----------------
// Block b owns output rows [64b, 64b+64); LDS f32 accumulator [64][132]. For each k: wave w
// handles cols [32w, 32w+32) (B-frags straight from L2-resident Wb); entries of bin (b,k) are
// processed in 16-slot batches: direct A-gather (16 rows x 64B segments), 8 MFMA, scatter C rows
// into LDS via ds_add_f32 (target row from packed sidx, broadcast by shfl). Epilogue: one
// coalesced f32 store of the 64 finished rows + fused BN-stats atomics (trickled).
__global__ __launch_bounds__(256, 4) void k_fconv(const u16* __restrict__ src,
                                                  const u16* __restrict__ Wb,
                                                  const u32* __restrict__ offs,
                                                  const u32* __restrict__ sidx,
                                                  float* __restrict__ acc,
                                                  float* __restrict__ stats) {
  __shared__ float accs[64][LDA];
  const int t = threadIdx.x, b = blockIdx.x;
  for (int i = t; i < 64 * LDA; i += 256) ((float*)accs)[i] = 0.f;
  __syncthreads();

  const int wave = t >> 6, lane = t & 63;
  const int lr = lane & 15, quad = lane >> 4;
  const int cb = wave * 32;  // wave's output-col base
  const u32 binb = (u32)b * KOFF;

  for (int k = 0; k < KOFF; ++k) {
    const u32 s = offs[binb + k], e = offs[binb + k + 1];
    if (s == e) continue;
    const u16* wk = Wb + (size_t)k * (CD * CD);
    bf16x8 bf[2][4];
#pragma unroll
    for (int nt = 0; nt < 2; ++nt)
#pragma unroll
      for (int kk = 0; kk < 4; ++kk)
        bf[nt][kk] = *(const bf16x8*)(wk + (cb + nt * 16 + lr) * CD + (kk * 4 + quad) * 8);

    for (u32 t0 = s; t0 < e; t0 += 16) {
      const u32 idx = t0 + (u32)lr;
      const bool valid = idx < e;
      const u32 px = sidx[valid ? idx : (e - 1)];
      const u32 row = px >> 6;
      const u32 trow = px & 63u;
      const u32 m = valid ? 0xffffffffu : 0u;
      uint4 a4[4];
#pragma unroll
      for (int kk = 0; kk < 4; ++kk) {
        uint4 av = *(const uint4*)(src + (size_t)row * CD + (kk * 4 + quad) * 8);
        av.x &= m;
        av.y &= m;
        av.z &= m;
        av.w &= m;
        a4[kk] = av;
      }
      f32x4 c0 = {}, c1 = {};
#pragma unroll
      for (int kk = 0; kk < 4; ++kk) {
        const bf16x8 a = *(const bf16x8*)&a4[kk];
        c0 = __builtin_amdgcn_mfma_f32_16x16x32_bf16(a, bf[0][kk], c0, 0, 0, 0);
        c1 = __builtin_amdgcn_mfma_f32_16x16x32_bf16(a, bf[1][kk], c1, 0, 0, 0);
      }
      // C/D layout (verified): col = lane&15, row = quad*4 + v. Scatter rows to LDS acc.
#pragma unroll
      for (int v = 0; v < 4; ++v) {
        const u32 tr = __shfl(trow, quad * 4 + v);
        atomicAdd(&accs[tr][cb + lr], c0[v]);
        atomicAdd(&accs[tr][cb + 16 + lr], c1[v]);
      }
    }
  }
  __syncthreads();

  {  // coalesced f32 write-out: thread t -> row t>>2, col-quarter t&3
    const int r = t >> 2, q = t & 3;
    float4* dst = (float4*)(acc + ((size_t)b * 64 + r) * CD + q * 32);
    const float* sr = &accs[r][q * 32];
#pragma unroll
    for (int j = 0; j < 8; ++j) dst[j] = *(const float4*)(sr + j * 4);
  }
  if (t < 128) {  // fused BN stats (256 atomics/block, trickled)
    float sx = 0.f, sq = 0.f;
    for (int r = 0; r < 64; ++r) {
      const float v = accs[r][t];
      sx += v;
      sq += v * v;
    }
    atomicAdd(&stats[t], sx);
    atomicAdd(&stats[128 + t], sq);
  }
}

// ---------------- BN finalize / apply ----------------
__global__ void k_finalize(const float* __restrict__ stats, const float* __restrict__ gamma,
                           const float* __restrict__ beta, float* __restrict__ scsh) {
  int c = threadIdx.x;
  float mean = stats[c] * (1.f / NPTS);
  float var = stats[128 + c] * (1.f / NPTS) - mean * mean;
  float sc = rsqrtf(var + 1e-5f) * gamma[c];
  scsh[c] = sc;
  scsh[128 + c] = beta[c] - mean * sc;
}

__device__ __forceinline__ float elu(float v) { return v > 0.f ? v : expf(v) - 1.f; }

__global__ __launch_bounds__(256) void k_apply_mid(const float* __restrict__ acc,
                                                   const float* __restrict__ scsh,
                                                   u16* __restrict__ y) {
  long i = ((long)blockIdx.x * 256 + threadIdx.x) * 4;
  int c = (int)(i & 127);
  float4 a = *(const float4*)(acc + i);
  float r0 = elu(a.x * scsh[c] + scsh[128 + c]);
  float r1 = elu(a.y * scsh[c + 1] + scsh[129 + c]);
  float r2 = elu(a.z * scsh[c + 2] + scsh[130 + c]);
  float r3 = elu(a.w * scsh[c + 3] + scsh[131 + c]);
  uint2 v;
  v.x = f2bf(r0) | ((u32)f2bf(r1) << 16);
  v.y = f2bf(r2) | ((u32)f2bf(r3) << 16);
  *(uint2*)(y + i) = v;
}

__global__ __launch_bounds__(256) void k_apply_final(const float* __restrict__ acc,
                                                     const float* __restrict__ scsh,
                                                     const float* __restrict__ x,
                                                     float* __restrict__ out) {
  long i = ((long)blockIdx.x * 256 + threadIdx.x) * 4;
  int c = (int)(i & 127);
  float4 a = *(const float4*)(acc + i);
  float4 rx = *(const float4*)(x + i);
  float4 o;
  o.x = elu(a.x * scsh[c] + scsh[128 + c] + rx.x);
  o.y = elu(a.y * scsh[c + 1] + scsh[129 + c] + rx.y);
  o.z = elu(a.z * scsh[c + 2] + scsh[130 + c] + rx.z);
  o.w = elu(a.w * scsh[c + 3] + scsh[131 + c] + rx.w);
  *(float4*)(out + i) = o;
}

// ---------------- host ----------------
extern "C" void kernel_launch(void* const* d_in, const int* in_sizes, int n_in,
                              void* d_out, int out_size, void* d_ws, size_t ws_size,
                              hipStream_t stream) {
  const float* x = (const float*)d_in[0];
  const float* W1 = (const float*)d_in[1];
  const float* g1 = (const float*)d_in[2];
  const float* b1 = (const float*)d_in[3];
  const float* W2 = (const float*)d_in[4];
  const float* g2 = (const float*)d_in[5];
  const float* b2 = (const float*)d_in[6];
  const int* m1i = (const int*)d_in[7];
  const int* m1o = (const int*)d_in[8];
  const int* m2i = (const int*)d_in[9];
  const int* m2o = (const int*)d_in[10];
  float* out = (float*)d_out;

  char* base = (char*)d_ws;
  size_t off = 0;
  auto alloc = [&](size_t bytes) -> void* {
    void* r = base + off;
    off = (off + bytes + 255) & ~(size_t)255;
    return r;
  };
  // xb doubles as the mid-activation buffer (dead after conv1's k_fconv).
  u16* xb = (u16*)alloc((size_t)NPTS * CD * 2);
  u16* Wb1 = (u16*)alloc((size_t)KOFF * CD * CD * 2);
  u16* Wb2 = (u16*)alloc((size_t)KOFF * CD * CD * 2);
  float* acc = (float*)alloc((size_t)NPTS * CD * 4);
  float* stats = (float*)alloc(256 * 4);
  float* scsh = (float*)alloc(256 * 4);
  u32* hist = (u32*)alloc((size_t)NBIN * 4);
  u32* cur = (u32*)alloc((size_t)NBIN * 4);  // contiguous with hist for one memset
  u32* offs = (u32*)alloc(((size_t)NBIN + 1) * 4);
  u32* bsum = (u32*)alloc(256 * 4);
  u32* sidx = (u32*)alloc((size_t)TOT * 4);

  k_convert_x<<<(NPTS * CD) / 2048, 256, 0, stream>>>(x, xb);
  k_convert_w<<<(KOFF * 2048 + 255) / 256, 256, 0, stream>>>(W1, Wb1);
  k_convert_w<<<(KOFF * 2048 + 255) / 256, 256, 0, stream>>>(W2, Wb2);

  auto run_conv = [&](const u16* srcm, const u16* Wbm, const int* mi, const int* mo) {
    hipMemsetAsync(stats, 0, 1024, stream);
    hipMemsetAsync(hist, 0, 2 * (size_t)NBIN * 4, stream);
    k_hist3<<<TOT / 256, 256, 0, stream>>>(mo, hist);
    k_scanA3<<<NBIN / 256, 256, 0, stream>>>(hist, offs, bsum);
    k_scanB3<<<1, 256, 0, stream>>>(bsum);
    k_scanC3<<<NBIN / 256, 256, 0, stream>>>(offs, bsum);
    k_rank3<<<TOT / 256, 256, 0, stream>>>(mi, mo, offs, cur, sidx);
    k_fconv<<<NBLK, 256, 0, stream>>>(srcm, Wbm, offs, sidx, acc, stats);
  };

  run_conv(xb, Wb1, m1i, m1o);
  k_finalize<<<1, 128, 0, stream>>>(stats, g1, b1, scsh);
  k_apply_mid<<<(NPTS * CD) / 1024, 256, 0, stream>>>(acc, scsh, xb);

  run_conv(xb, Wb2, m2i, m2o);
  k_finalize<<<1, 128, 0, stream>>>(stats, g2, b2, scsh);
  k_apply_final<<<(NPTS * CD) / 1024, 256, 0, stream>>>(acc, scsh, x, out);
}

// Round 8
// 2923.780 us; speedup vs baseline: 1.1767x; 1.1767x over previous
//
#include <hip/hip_runtime.h>

typedef unsigned short u16;
typedef unsigned int u32;

#define NPTS 131072
#define CD 128
#define KOFF 27
#define MMAP 65536
#define TOT (KOFF * MMAP)      // 1769472 entries per conv
#define NBLK 2048              // output row blocks (64 rows each)
#define NBIN (NBLK * KOFF)     // 55296 sort bins
#define LDA 132                // LDS f32 accumulator row stride

__device__ __forceinline__ u16 f2bf(float f) {  // f32 -> bf16 RNE
  u32 u = __float_as_uint(f);
  u32 r = (u + 0x7fffu + ((u >> 16) & 1u)) >> 16;
  return (u16)r;
}

typedef __attribute__((ext_vector_type(8))) short bf16x8;
typedef __attribute__((ext_vector_type(4))) float f32x4;

// ---------------- dtype conversion ----------------
__global__ __launch_bounds__(256) void k_convert_x(const float* __restrict__ x,
                                                   u16* __restrict__ xb) {
  long i = ((long)blockIdx.x * 256 + threadIdx.x) * 8;
  float4 a = *(const float4*)(x + i);
  float4 b = *(const float4*)(x + i + 4);
  uint4 v;
  v.x = f2bf(a.x) | ((u32)f2bf(a.y) << 16);
  v.y = f2bf(a.z) | ((u32)f2bf(a.w) << 16);
  v.z = f2bf(b.x) | ((u32)f2bf(b.y) << 16);
  v.w = f2bf(b.z) | ((u32)f2bf(b.w) << 16);
  *(uint4*)(xb + i) = v;
}

// W [K][ci][co] f32 -> Wb [K][co][ci] bf16
__global__ __launch_bounds__(256) void k_convert_w(const float* __restrict__ W,
                                                   u16* __restrict__ Wb) {
  int idx = blockIdx.x * 256 + threadIdx.x;
  if (idx >= KOFF * 2048) return;
  int k = idx >> 11;
  int rem = idx & 2047;
  int co = rem >> 4;
  int cc = rem & 15;
  const float* ws = W + (long)k * (CD * CD) + (long)(cc * 8) * CD + co;
  u16 t[8];
#pragma unroll
  for (int j = 0; j < 8; ++j) t[j] = f2bf(ws[j * CD]);
  uint4 v;
  v.x = t[0] | ((u32)t[1] << 16);
  v.y = t[2] | ((u32)t[3] << 16);
  v.z = t[4] | ((u32)t[5] << 16);
  v.w = t[6] | ((u32)t[7] << 16);
  ((uint4*)Wb)[idx] = v;
}

// ---------------- counting sort over (row_block, k) bins ----------------
__global__ __launch_bounds__(256) void k_hist3(const int* __restrict__ mo,
                                               u32* __restrict__ hist) {
  int i = blockIdx.x * 256 + threadIdx.x;  // grid = TOT/256 exact
  u32 key = ((u32)mo[i] >> 6) * KOFF + (u32)(i >> 16);
  atomicAdd(&hist[key], 1u);
}

__global__ __launch_bounds__(256) void k_scanA3(const u32* __restrict__ hist,
                                                u32* __restrict__ offs,
                                                u32* __restrict__ bsum) {
  __shared__ u32 sh[256];
  int t = threadIdx.x, b = blockIdx.x, i = b * 256 + t;  // 216 blocks, NBIN exact
  u32 v = hist[i];
  u32 run = v;
  sh[t] = run;
  __syncthreads();
  for (int d = 1; d < 256; d <<= 1) {
    u32 y = (t >= d) ? sh[t - d] : 0u;
    __syncthreads();
    run += y;
    sh[t] = run;
    __syncthreads();
  }
  offs[i] = run - v;
  if (t == 255) bsum[b] = run;
}

__global__ __launch_bounds__(256) void k_scanB3(u32* __restrict__ bsum) {
  __shared__ u32 sh[256];
  int t = threadIdx.x;
  u32 v = (t < 216) ? bsum[t] : 0u;
  u32 run = v;
  sh[t] = run;
  __syncthreads();
  for (int d = 1; d < 256; d <<= 1) {
    u32 y = (t >= d) ? sh[t - d] : 0u;
    __syncthreads();
    run += y;
    sh[t] = run;
    __syncthreads();
  }
  if (t < 216) bsum[t] = run - v;
}

__global__ __launch_bounds__(256) void k_scanC3(u32* __restrict__ offs,
                                                const u32* __restrict__ bsum) {
  int t = threadIdx.x, b = blockIdx.x, i = b * 256 + t;
  offs[i] += bsum[b];
  if (i == 0) offs[NBIN] = (u32)TOT;
}

// sidx[rank] = packed entry: (input_row << 6) | (out_row & 63).
__global__ __launch_bounds__(256) void k_rank3(const int* __restrict__ mi,
                                               const int* __restrict__ mo,
                                               const u32* __restrict__ offs,
                                               u32* __restrict__ cur,
                                               u32* __restrict__ sidx) {
  int i = blockIdx.x * 256 + threadIdx.x;
  u32 o = (u32)mo[i];
  u32 key = (o >> 6) * KOFF + (u32)(i >> 16);
  u32 r = offs[key] + atomicAdd(&cur[key], 1u);
  sidx[r] = ((u32)mi[i] << 6) | (o & 63u);
}

// ---------------- fused implicit-GEMM sparse conv, software-pipelined ----------------
// Block b owns output rows [64b, 64b+64); LDS f32 accumulator [64][132]. Bins (b,k) are
// contiguous in sidx, so the 16-entry batch stream is flat. Pipeline: iter i computes
// batch i+2 meta + issues its sidx load; issues batch i+1's A-gathers; MFMAs batch i;
// B (single bank, wave's 32-col slice) reloaded right after the last MFMA that reads it.
// Padded lanes gather row ek-1 (finite); the per-v LDS add is predicated instead.
__global__ __launch_bounds__(256, 4) void k_fconv2(const u16* __restrict__ src,
                                                   const u16* __restrict__ Wb,
                                                   const u32* __restrict__ offs,
                                                   const u32* __restrict__ sidx,
                                                   float* __restrict__ acc,
                                                   float* __restrict__ statsP) {
  __shared__ float accs[64][LDA];
  const int t = threadIdx.x, b = blockIdx.x;
  for (int i = t; i < 64 * LDA; i += 256) ((float*)accs)[i] = 0.f;
  __syncthreads();

  const int wave = t >> 6, lane = t & 63;
  const int lr = lane & 15, quad = lane >> 4;
  const int cb = wave * 32;
  const u32 binb = (u32)b * KOFF;

  const u32 eoff = offs[binb + (lane <= KOFF ? lane : KOFF)];  // lane l: offs[binb+l]
  const u32 tend = __shfl(eoff, KOFF);
  u32 t0 = __shfl(eoff, 0);

  auto gather = [&](u32 px, uint4* A) {
    const u16* rp = src + (size_t)(px >> 6) * CD;
#pragma unroll
    for (int kk = 0; kk < 4; ++kk) A[kk] = *(const uint4*)(rp + (kk * 4 + quad) * 8);
  };
  auto loadB = [&](int k_, bf16x8 B[2][4]) {
    const u16* wk = Wb + (size_t)k_ * (CD * CD);
#pragma unroll
    for (int nt = 0; nt < 2; ++nt)
#pragma unroll
      for (int kk = 0; kk < 4; ++kk)
        B[nt][kk] = *(const bf16x8*)(wk + (cb + nt * 16 + lr) * CD + (kk * 4 + quad) * 8);
  };
  // advance batch meta: next start = min(t+16, ek); then skip to the bin containing it
  auto adv = [&](u32 ti, int ki, u32 eki, u32& tn, int& kn, u32& ekn) {
    tn = ti + 16;
    if (tn > eki) tn = eki;
    kn = ki;
    ekn = eki;
    while (kn < KOFF && ekn <= tn) {
      ++kn;
      if (kn < KOFF) ekn = __shfl(eoff, kn + 1);
    }
  };

  if (t0 < tend) {
    int k0 = 0;
    u32 ek0 = __shfl(eoff, 1);
    while (k0 < KOFF && ek0 <= t0) {
      ++k0;
      if (k0 < KOFF) ek0 = __shfl(eoff, k0 + 1);
    }
    u32 px0 = sidx[min(t0 + (u32)lr, ek0 - 1)];
    u32 t1;
    int k1;
    u32 ek1;
    adv(t0, k0, ek0, t1, k1, ek1);
    u32 px1 = (k1 < KOFF) ? sidx[min(t1 + (u32)lr, ek1 - 1)] : 0u;
    uint4 A0[4];
    gather(px0, A0);
    bf16x8 B[2][4];
    loadB(k0, B);
    uint4 A1[4];

    while (true) {
      const bool more = (k1 < KOFF);
      u32 t2 = 0, ek2 = 0, px2 = 0;
      int k2 = KOFF;
      if (more) {
        adv(t1, k1, ek1, t2, k2, ek2);
        if (k2 < KOFF) px2 = sidx[min(t2 + (u32)lr, ek2 - 1)];
        gather(px1, A1);
      }
      f32x4 c0 = {}, c1 = {};
#pragma unroll
      for (int kk = 0; kk < 4; ++kk) {
        const bf16x8 a = *(const bf16x8*)&A0[kk];
        c0 = __builtin_amdgcn_mfma_f32_16x16x32_bf16(a, B[0][kk], c0, 0, 0, 0);
        c1 = __builtin_amdgcn_mfma_f32_16x16x32_bf16(a, B[1][kk], c1, 0, 0, 0);
      }
      if (more && k1 != k0) loadB(k1, B);  // WAR on B regs orders this after the MFMAs
      // C/D layout: col = lane&15, row(entry) = quad*4+v. Predicated scatter into LDS acc.
#pragma unroll
      for (int v = 0; v < 4; ++v) {
        const u32 tr = __shfl(px0, quad * 4 + v) & 63u;
        if (t0 + (u32)(quad * 4 + v) < ek0) {
          atomicAdd(&accs[tr][cb + lr], c0[v]);
          atomicAdd(&accs[tr][cb + 16 + lr], c1[v]);
        }
      }
      if (!more) break;
      t0 = t1; k0 = k1; ek0 = ek1; px0 = px1;
      t1 = t2; k1 = k2; ek1 = ek2; px1 = px2;
#pragma unroll
      for (int kk = 0; kk < 4; ++kk) A0[kk] = A1[kk];
    }
  }
  __syncthreads();

  {  // coalesced f32 write-out: thread t -> row t>>2, col-quarter t&3
    const int r = t >> 2, q = t & 3;
    float4* dst = (float4*)(acc + ((size_t)b * 64 + r) * CD + q * 32);
    const float* sr = &accs[r][q * 32];
#pragma unroll
    for (int j = 0; j < 8; ++j) dst[j] = *(const float4*)(sr + j * 4);
  }
  if (t < 128) {  // bucketed BN stats: 64 buckets x 256ch, 32 blocks per bucket
    float sx = 0.f, sq = 0.f;
    for (int r = 0; r < 64; ++r) {
      const float v = accs[r][t];
      sx += v;
      sq += v * v;
    }
    float* bkt = statsP + (size_t)(b & 63) * 256;
    atomicAdd(&bkt[t], sx);
    atomicAdd(&bkt[128 + t], sq);
  }
}

// ---------------- BN finalize / apply ----------------
__global__ void k_finalize(const float* __restrict__ statsP, const float* __restrict__ gamma,
                           const float* __restrict__ beta, float* __restrict__ scsh) {
  int c = threadIdx.x;  // 128
  float s = 0.f, q = 0.f;
  for (int g = 0; g < 64; ++g) {
    s += statsP[g * 256 + c];
    q += statsP[g * 256 + 128 + c];
  }
  float mean = s * (1.f / NPTS);
  float var = q * (1.f / NPTS) - mean * mean;
  float sc = rsqrtf(var + 1e-5f) * gamma[c];
  scsh[c] = sc;
  scsh[128 + c] = beta[c] - mean * sc;
}

__device__ __forceinline__ float elu(float v) { return v > 0.f ? v : expf(v) - 1.f; }

__global__ __launch_bounds__(256) void k_apply_mid(const float* __restrict__ acc,
                                                   const float* __restrict__ scsh,
                                                   u16* __restrict__ y) {
  long i = ((long)blockIdx.x * 256 + threadIdx.x) * 4;
  int c = (int)(i & 127);
  float4 a = *(const float4*)(acc + i);
  float r0 = elu(a.x * scsh[c] + scsh[128 + c]);
  float r1 = elu(a.y * scsh[c + 1] + scsh[129 + c]);
  float r2 = elu(a.z * scsh[c + 2] + scsh[130 + c]);
  float r3 = elu(a.w * scsh[c + 3] + scsh[131 + c]);
  uint2 v;
  v.x = f2bf(r0) | ((u32)f2bf(r1) << 16);
  v.y = f2bf(r2) | ((u32)f2bf(r3) << 16);
  *(uint2*)(y + i) = v;
}

__global__ __launch_bounds__(256) void k_apply_final(const float* __restrict__ acc,
                                                     const float* __restrict__ scsh,
                                                     const float* __restrict__ x,
                                                     float* __restrict__ out) {
  long i = ((long)blockIdx.x * 256 + threadIdx.x) * 4;
  int c = (int)(i & 127);
  float4 a = *(const float4*)(acc + i);
  float4 rx = *(const float4*)(x + i);
  float4 o;
  o.x = elu(a.x * scsh[c] + scsh[128 + c] + rx.x);
  o.y = elu(a.y * scsh[c + 1] + scsh[129 + c] + rx.y);
  o.z = elu(a.z * scsh[c + 2] + scsh[130 + c] + rx.z);
  o.w = elu(a.w * scsh[c + 3] + scsh[131 + c] + rx.w);
  *(float4*)(out + i) = o;
}

// ---------------- host ----------------
extern "C" void kernel_launch(void* const* d_in, const int* in_sizes, int n_in,
                              void* d_out, int out_size, void* d_ws, size_t ws_size,
                              hipStream_t stream) {
  const float* x = (const float*)d_in[0];
  const float* W1 = (const float*)d_in[1];
  const float* g1 = (const float*)d_in[2];
  const float* b1 = (const float*)d_in[3];
  const float* W2 = (const float*)d_in[4];
  const float* g2 = (const float*)d_in[5];
  const float* b2 = (const float*)d_in[6];
  const int* m1i = (const int*)d_in[7];
  const int* m1o = (const int*)d_in[8];
  const int* m2i = (const int*)d_in[9];
  const int* m2o = (const int*)d_in[10];
  float* out = (float*)d_out;

  char* base = (char*)d_ws;
  size_t off = 0;
  auto alloc = [&](size_t bytes) -> void* {
    void* r = base + off;
    off = (off + bytes + 255) & ~(size_t)255;
    return r;
  };
  // xb doubles as the mid-activation buffer (dead after conv1's k_fconv2).
  u16* xb = (u16*)alloc((size_t)NPTS * CD * 2);
  u16* Wb1 = (u16*)alloc((size_t)KOFF * CD * CD * 2);
  u16* Wb2 = (u16*)alloc((size_t)KOFF * CD * CD * 2);
  float* acc = (float*)alloc((size_t)NPTS * CD * 4);
  float* scsh = (float*)alloc(256 * 4);
  u32* hist = (u32*)alloc((size_t)NBIN * 4);
  u32* cur = (u32*)alloc((size_t)NBIN * 4);        // contiguous with hist
  float* statsP = (float*)alloc(64 * 256 * 4);     // contiguous with cur -> one memset
  size_t msSize = (size_t)((char*)base + off - (char*)hist);
  u32* offs = (u32*)alloc(((size_t)NBIN + 1) * 4);
  u32* bsum = (u32*)alloc(256 * 4);
  u32* sidx = (u32*)alloc((size_t)TOT * 4);

  k_convert_x<<<(NPTS * CD) / 2048, 256, 0, stream>>>(x, xb);
  k_convert_w<<<(KOFF * 2048 + 255) / 256, 256, 0, stream>>>(W1, Wb1);
  k_convert_w<<<(KOFF * 2048 + 255) / 256, 256, 0, stream>>>(W2, Wb2);

  auto run_conv = [&](const u16* srcm, const u16* Wbm, const int* mi, const int* mo) {
    hipMemsetAsync(hist, 0, msSize, stream);  // hist + cur + statsP
    k_hist3<<<TOT / 256, 256, 0, stream>>>(mo, hist);
    k_scanA3<<<NBIN / 256, 256, 0, stream>>>(hist, offs, bsum);
    k_scanB3<<<1, 256, 0, stream>>>(bsum);
    k_scanC3<<<NBIN / 256, 256, 0, stream>>>(offs, bsum);
    k_rank3<<<TOT / 256, 256, 0, stream>>>(mi, mo, offs, cur, sidx);
    k_fconv2<<<NBLK, 256, 0, stream>>>(srcm, Wbm, offs, sidx, acc, statsP);
  };

  run_conv(xb, Wb1, m1i, m1o);
  k_finalize<<<1, 128, 0, stream>>>(statsP, g1, b1, scsh);
  k_apply_mid<<<(NPTS * CD) / 1024, 256, 0, stream>>>(acc, scsh, xb);

  run_conv(xb, Wb2, m2i, m2o);
  k_finalize<<<1, 128, 0, stream>>>(statsP, g2, b2, scsh);
  k_apply_final<<<(NPTS * CD) / 1024, 256, 0, stream>>>(acc, scsh, x, out);
}